// Round 8
// baseline (567.248 us; speedup 1.0000x reference)
//
#include <hip/hip_runtime.h>
#include <math.h>

#define B_ 16
#define A_ 32
#define G_ 512
#define S_ 4096
#define M_ 8
#define BS_ 65536
#define KC_ 640      // concat K: 512 normed + 100 OH + 28 pad
#define NG_ 1536

typedef _Float16 half8 __attribute__((ext_vector_type(8)));
typedef _Float16 half4v __attribute__((ext_vector_type(4)));
typedef _Float16 half2v __attribute__((ext_vector_type(2)));
typedef float floatx4 __attribute__((ext_vector_type(4)));
typedef float floatx16 __attribute__((ext_vector_type(16)));

typedef const __attribute__((address_space(1))) void* gas_t;
typedef __attribute__((address_space(3))) void* las_t;

// ---------------- helpers ----------------
__device__ __forceinline__ float wave_sum_f(float v){
#pragma unroll
  for (int o = 32; o > 0; o >>= 1) v += __shfl_xor(v, o);
  return v;
}
__device__ __forceinline__ float wave_max_f(float v){
#pragma unroll
  for (int o = 32; o > 0; o >>= 1) v = fmaxf(v, __shfl_xor(v, o));
  return v;
}
__device__ __forceinline__ float sigmoidf_(float x){ return 1.f/(1.f+__expf(-x)); }
__device__ __forceinline__ float tanhf_(float x){ return 1.f - 2.f/(__expf(2.f*x)+1.f); }

// ---------------- K0a: fp32 -> fp16 convert (n % 4 == 0) --------------------
__global__ __launch_bounds__(256) void k_cvt(const float* __restrict__ s,
                                             _Float16* __restrict__ d, int n){
  int i = (blockIdx.x*256 + threadIdx.x)*4;
  if (i >= n) return;
  float4 v = *(const float4*)(s+i);
  half4v o; o[0]=(_Float16)v.x; o[1]=(_Float16)v.y; o[2]=(_Float16)v.z; o[3]=(_Float16)v.w;
  *(half4v*)(d+i) = o;
}

// ---------------- K0b: build Wcat[1536][640] = [W_hh | W_ih(r,z) | 0] -------
__global__ __launch_bounds__(64) void k_buildw(const float* __restrict__ Whh,
                                               const float* __restrict__ Wih,
                                               _Float16* __restrict__ Wcat){
  int j = blockIdx.x;
  for (int p = threadIdx.x; p < KC_; p += 64){
    float v = 0.f;
    if (p < 512) v = Whh[(size_t)j*512 + p];
    else if (p < 612 && j < 1024) v = Wih[(size_t)j*100 + (p - 512)];
    Wcat[(size_t)j*KC_ + p] = (_Float16)v;
  }
}

// ---------------- K0c: Pn[100][512] — transposed prefix table for i_n -------
__global__ __launch_bounds__(256) void k_pn(const float* __restrict__ Wih,
                                            float* __restrict__ Pn){
  int d = blockIdx.x*256 + threadIdx.x;
  if (d >= 512) return;
  const float* src = Wih + (size_t)(1024 + d)*100;
#pragma unroll
  for (int f = 0; f < 5; ++f){
    int off = f*20;
    float run = 0.f;
    for (int k = 0; k < 20; ++k){
      run += src[off + k];
      Pn[(size_t)(off + k)*512 + d] = run;
    }
  }
}

// ---------------- K1: MFMA prep — swvs GEMM + LN + counts + OH --------------
__global__ __launch_bounds__(256) void k_prep_mfma(
    const float* __restrict__ vf, const float* __restrict__ mask,
    const float* __restrict__ eoh, const float* __restrict__ subs,
    const float* __restrict__ ln_g, const float* __restrict__ ln_b,
    _Float16* __restrict__ Abuf, int* __restrict__ cpk){
  __shared__ _Float16 s_mvfT[G_*A_];   // [g][a], masked vf, 32 KB
  __shared__ _Float16 s_sm[128*A_];    // [s][a], raw subs, 8 KB
  __shared__ float s_m[A_];
  __shared__ float s_e[A_*5];
  __shared__ float s_ssum[128];
  __shared__ float s_red1[4][16];
  __shared__ float s_red2[4][16];
  int tid = threadIdx.x;
  int bx = blockIdx.x, b = blockIdx.y;
  int lane = tid & 63, w = tid >> 6;
  int q = lane >> 4, l15 = lane & 15;
  size_t row0 = (size_t)b*S_ + (size_t)bx*128;
  if (tid < A_)   s_m[tid] = mask[b*A_ + tid];
  if (tid < A_*5) s_e[tid] = eoh[b*A_*5 + tid];
  __syncthreads();
  {
    int p = tid & 15, gseg = tid >> 4;
    float mk0 = s_m[2*p], mk1 = s_m[2*p+1];
    const float* v0 = vf + ((size_t)b*A_ + 2*p)*G_ + gseg*32;
    const float* v1 = v0 + G_;
#pragma unroll
    for (int i = 0; i < 32; ++i){
      int g = gseg*32 + i;
      half2v h; h[0] = (_Float16)(v0[i]*mk0); h[1] = (_Float16)(v1[i]*mk1);
      *(half2v*)(s_mvfT + g*A_ + 2*p) = h;
    }
  }
  {
    int s = tid >> 1, hh = tid & 1;
    const float* sp = subs + (row0 + s)*A_ + hh*16;
#pragma unroll
    for (int i = 0; i < 16; i += 2){
      half2v h; h[0] = (_Float16)sp[i]; h[1] = (_Float16)sp[i+1];
      *(half2v*)(s_sm + s*A_ + hh*16 + i) = h;
    }
  }
  __syncthreads();
  if (tid < 128){
    int s = tid;
    float ssum = 0.f, c0=0.f, c1=0.f, c2=0.f, c3=0.f, c4=0.f;
#pragma unroll
    for (int a = 0; a < A_; ++a){
      float v = (float)s_sm[s*A_ + a];
      ssum += v * s_m[a];
      c0 += v * s_e[a*5+0]; c1 += v * s_e[a*5+1]; c2 += v * s_e[a*5+2];
      c3 += v * s_e[a*5+3]; c4 += v * s_e[a*5+4];
    }
    int cc[5];
    cc[0] = min(max((int)(c0+0.5f),0),19); cc[1] = min(max((int)(c1+0.5f),0),19);
    cc[2] = min(max((int)(c2+0.5f),0),19); cc[3] = min(max((int)(c3+0.5f),0),19);
    cc[4] = min(max((int)(c4+0.5f),0),19);
    cpk[row0 + s] = cc[0] | (cc[1]<<6) | (cc[2]<<12) | (cc[3]<<18) | (cc[4]<<24);
    s_ssum[s] = ssum;
    _Float16* dst = Abuf + (row0 + s)*KC_ + 512;
#pragma unroll
    for (int t = 0; t < 16; ++t){
      half8 hv;
#pragma unroll
      for (int u = 0; u < 8; ++u){
        int k = t*8 + u;
        float v = 0.f;
        if (k < 100){ int f = k/20, l = k - f*20; v = (l <= cc[f]) ? 1.f : 0.f; }
        hv[u] = (_Float16)v;
      }
      *(half8*)(dst + t*8) = hv;
    }
  }
  half8 bf[8]; float lng[8], lnb[8];
#pragma unroll
  for (int t = 0; t < 8; ++t){
    int g = w*128 + t*16 + l15;
    bf[t] = *(const half8*)(s_mvfT + g*A_ + q*8);
    lng[t] = ln_g[g]; lnb[t] = ln_b[g];
  }
  __syncthreads();
  for (int gi = 0; gi < 8; ++gi){
    half8 af = *(const half8*)(s_sm + (gi*16 + l15)*A_ + q*8);
    floatx4 c[8];
#pragma unroll
    for (int t = 0; t < 8; ++t){
      floatx4 z = {0.f, 0.f, 0.f, 0.f};
      c[t] = __builtin_amdgcn_mfma_f32_16x16x32_f16(af, bf[t], z, 0, 0, 0);
    }
    float p1[4] = {0.f,0.f,0.f,0.f}, p2[4] = {0.f,0.f,0.f,0.f};
#pragma unroll
    for (int t = 0; t < 8; ++t)
#pragma unroll
      for (int r = 0; r < 4; ++r){ float v = c[t][r]; p1[r] += v; p2[r] += v*v; }
#pragma unroll
    for (int off = 1; off < 16; off <<= 1)
#pragma unroll
      for (int r = 0; r < 4; ++r){
        p1[r] += __shfl_xor(p1[r], off);
        p2[r] += __shfl_xor(p2[r], off);
      }
    if (l15 == 0){
#pragma unroll
      for (int r = 0; r < 4; ++r){ s_red1[w][q*4+r] = p1[r]; s_red2[w][q*4+r] = p2[r]; }
    }
    __syncthreads();
#pragma unroll
    for (int r = 0; r < 4; ++r){
      int sl = gi*16 + q*4 + r;
      int rr = q*4 + r;
      float t1 = s_red1[0][rr] + s_red1[1][rr] + s_red1[2][rr] + s_red1[3][rr];
      float t2 = s_red2[0][rr] + s_red2[1][rr] + s_red2[2][rr] + s_red2[3][rr];
      float inv = 1.f/(s_ssum[sl] + 1e-4f);
      float mu = t1*inv*(1.f/512.f);
      float var = t2*inv*inv*(1.f/512.f) - mu*mu;
      float rs = rsqrtf(var + 1e-5f);
      _Float16* orow = Abuf + (row0 + sl)*KC_;
#pragma unroll
      for (int t = 0; t < 8; ++t){
        float o = (c[t][r]*inv - mu)*rs*lng[t] + lnb[t];
        orow[w*128 + t*16 + l15] = (_Float16)o;
      }
    }
    __syncthreads();
  }
}

// ---------------- K2: fused gh GEMM (3 gates, 32x32x16) + GRU elementwise ---
// grid (8, 512), 256 thr. xcd = bx; mt = bx*64 + (by>>3), dt = by&7.
// Block tile 128m x 192n (3 gates x 64 d). Waves 2x2: wave 64m x 96n as
// 2x3 grid of 32x32 tiles -> acc 6x16, 12 MFMA per 10 ds_read_b128 (38.4 F/B).
// LDS swizzle ku^((r>>1)&3): conflict-free (2-way) for 32-row frag reads.
__global__ __launch_bounds__(256) void k_gru_fused(
    const _Float16* __restrict__ Abuf, const _Float16* __restrict__ Wcat,
    const float* __restrict__ Pn, const float* __restrict__ bih,
    const float* __restrict__ bhh, const int* __restrict__ cpk,
    _Float16* __restrict__ H){
  __shared__ _Float16 smA[128*32];   // 8 KB
  __shared__ _Float16 smB[192*32];   // 12 KB
  int tid = threadIdx.x;
  int lane = tid & 63, wvid = tid >> 6;      // 4 waves
  int wm = wvid & 1, wn = wvid >> 1;         // 2x2
  int l31 = lane & 31, lhi = lane >> 5;
  int mt = blockIdx.x*64 + (blockIdx.y >> 3);
  int dt = blockIdx.y & 7;
  int m0 = mt*128, n0 = dt*64;
  floatx16 acc[3][2] = {};
  int offA[2][2], offB[3][2];
#pragma unroll
  for (int mi = 0; mi < 2; ++mi){
    int r = wm*64 + mi*32 + l31;
#pragma unroll
    for (int c = 0; c < 2; ++c)
      offA[mi][c] = (r*4 + ((c*2 + lhi) ^ ((r>>1)&3)))*8;
  }
#pragma unroll
  for (int g = 0; g < 3; ++g){
    int rb = g*64 + wn*32 + l31;
#pragma unroll
    for (int c = 0; c < 2; ++c)
      offB[g][c] = (rb*4 + ((c*2 + lhi) ^ ((rb>>1)&3)))*8;
  }
  // staging: A 8 segs (wave does wvid, wvid+4); B 12 segs (wave does wvid*3..+2)
  const _Float16* gA[2]; int sAo[2];
#pragma unroll
  for (int t = 0; t < 2; ++t){
    int seg = wvid + t*4;
    int u = seg*64 + lane;
    int r = u >> 2, c = (u & 3) ^ ((r >> 1) & 3);
    gA[t] = Abuf + (size_t)(m0 + r)*KC_ + c*8;
    sAo[t] = seg*512;
  }
  const _Float16* gB[3]; int sBo[3];
#pragma unroll
  for (int t = 0; t < 3; ++t){
    int seg = wvid*3 + t;
    int u = seg*64 + lane;
    int rb = u >> 2, c = (u & 3) ^ ((rb >> 1) & 3);
    int grow = (rb >> 6)*512 + n0 + (rb & 63);
    gB[t] = Wcat + (size_t)grow*KC_ + c*8;
    sBo[t] = seg*512;
  }
  for (int kc = 0; kc < KC_; kc += 32){
#pragma unroll
    for (int t = 0; t < 2; ++t)
      __builtin_amdgcn_global_load_lds((gas_t)(gA[t] + kc), (las_t)(smA + sAo[t]), 16, 0, 0);
#pragma unroll
    for (int t = 0; t < 3; ++t)
      __builtin_amdgcn_global_load_lds((gas_t)(gB[t] + kc), (las_t)(smB + sBo[t]), 16, 0, 0);
    __syncthreads();
    half8 af[2][2], bfv[3][2];
#pragma unroll
    for (int mi = 0; mi < 2; ++mi)
#pragma unroll
      for (int c = 0; c < 2; ++c) af[mi][c] = *(const half8*)(smA + offA[mi][c]);
#pragma unroll
    for (int g = 0; g < 3; ++g)
#pragma unroll
      for (int c = 0; c < 2; ++c) bfv[g][c] = *(const half8*)(smB + offB[g][c]);
#pragma unroll
    for (int g = 0; g < 3; ++g)
#pragma unroll
      for (int mi = 0; mi < 2; ++mi)
#pragma unroll
        for (int c = 0; c < 2; ++c)
          acc[g][mi] = __builtin_amdgcn_mfma_f32_32x32x16_f16(af[mi][c], bfv[g][c], acc[g][mi], 0, 0, 0);
    __syncthreads();
  }
  // epilogue: one d per lane; C layout col=lane&31, row=(rr&3)+8*(rr>>2)+4*lhi
  int d = n0 + wn*32 + l31;
  float br  = bih[d] + bhh[d];
  float bz  = bih[512+d] + bhh[512+d];
  float bnh = bhh[1024+d];
  float bni = bih[1024+d];
#pragma unroll
  for (int mi = 0; mi < 2; ++mi){
#pragma unroll
    for (int rr = 0; rr < 16; ++rr){
      int m = m0 + wm*64 + mi*32 + (rr&3) + 8*(rr>>2) + 4*lhi;
      int cp = cpk[m];
      int k0 =  (cp      ) & 63;
      int k1 = ((cp >> 6 ) & 63) + 20;
      int k2 = ((cp >> 12) & 63) + 40;
      int k3 = ((cp >> 18) & 63) + 60;
      int k4 = ((cp >> 24) & 63) + 80;
      float in_ = bni + Pn[(size_t)k0*512 + d] + Pn[(size_t)k1*512 + d]
                + Pn[(size_t)k2*512 + d] + Pn[(size_t)k3*512 + d]
                + Pn[(size_t)k4*512 + d];
      float gr = acc[0][mi][rr] + br;
      float gz = acc[1][mi][rr] + bz;
      float hn = acc[2][mi][rr] + bnh;
      float rrv = sigmoidf_(gr);
      float zz  = sigmoidf_(gz);
      float nn  = tanhf_(in_ + rrv*hn);
      float hp = (float)Abuf[(size_t)m*KC_ + d];
      H[(size_t)m*G_ + d] = (_Float16)((1.f-zz)*nn + zz*hp);
    }
  }
}

// ---------------- K3: FF fp16 MFMA GEMM (32x32x16)  Out = relu(A@W^T+b) -----
// K=512, N=512. grid (8, 256): xcd=bx; mt = bx*64 + (by>>2), nt = by&3.
// Block 128x128, waves 2x2, wave 64x64 as 2x2 grid of 32x32 tiles.
__global__ __launch_bounds__(256) void k_gemm(
    const _Float16* __restrict__ A, const _Float16* __restrict__ W,
    const float* __restrict__ bias, _Float16* __restrict__ Out){
  __shared__ _Float16 smA[128*32];
  __shared__ _Float16 smB[128*32];
  int tid = threadIdx.x;
  int lane = tid & 63, wvid = tid >> 6;
  int wm = wvid & 1, wn = wvid >> 1;
  int l31 = lane & 31, lhi = lane >> 5;
  int mt = blockIdx.x*64 + (blockIdx.y >> 2);
  int nt = blockIdx.y & 3;
  int m0 = mt*128, n0 = nt*128;
  floatx16 acc[2][2] = {};
  int offA[2][2], offB[2][2];
#pragma unroll
  for (int mi = 0; mi < 2; ++mi){
    int r = wm*64 + mi*32 + l31;
    int rb = wn*64 + mi*32 + l31;
#pragma unroll
    for (int c = 0; c < 2; ++c){
      offA[mi][c] = (r*4 + ((c*2 + lhi) ^ ((r>>1)&3)))*8;
      offB[mi][c] = (rb*4 + ((c*2 + lhi) ^ ((rb>>1)&3)))*8;
    }
  }
  const _Float16 *gA[2], *gB[2]; int uo[2];
#pragma unroll
  for (int t = 0; t < 2; ++t){
    int seg = wvid*2 + t;
    int u = seg*64 + lane;
    int r = u >> 2, c = (u & 3) ^ ((r >> 1) & 3);
    uo[t] = seg*512;
    gA[t] = A + (size_t)(m0 + r)*G_ + c*8;
    gB[t] = W + (size_t)(n0 + r)*G_ + c*8;
  }
  for (int kc = 0; kc < G_; kc += 32){
#pragma unroll
    for (int t = 0; t < 2; ++t){
      __builtin_amdgcn_global_load_lds((gas_t)(gA[t] + kc), (las_t)(smA + uo[t]), 16, 0, 0);
      __builtin_amdgcn_global_load_lds((gas_t)(gB[t] + kc), (las_t)(smB + uo[t]), 16, 0, 0);
    }
    __syncthreads();
    half8 af[2][2], bfv[2][2];
#pragma unroll
    for (int mi = 0; mi < 2; ++mi)
#pragma unroll
      for (int c = 0; c < 2; ++c){
        af[mi][c] = *(const half8*)(smA + offA[mi][c]);
        bfv[mi][c] = *(const half8*)(smB + offB[mi][c]);
      }
#pragma unroll
    for (int mi = 0; mi < 2; ++mi)
#pragma unroll
      for (int nj = 0; nj < 2; ++nj)
#pragma unroll
        for (int c = 0; c < 2; ++c)
          acc[mi][nj] = __builtin_amdgcn_mfma_f32_32x32x16_f16(af[mi][c], bfv[nj][c], acc[mi][nj], 0, 0, 0);
    __syncthreads();
  }
#pragma unroll
  for (int nj = 0; nj < 2; ++nj){
    int n = n0 + wn*64 + nj*32 + l31;
    float bv = bias[n];
#pragma unroll
    for (int mi = 0; mi < 2; ++mi){
#pragma unroll
      for (int rr = 0; rr < 16; ++rr){
        int m = m0 + wm*64 + mi*32 + (rr&3) + 8*(rr>>2) + 4*lhi;
        Out[(size_t)m*G_ + n] = (_Float16)fmaxf(acc[mi][nj][rr] + bv, 0.f);
      }
    }
  }
}

// ---------------- K4: final LN + score (fp16 in, fp32 out) ------------------
__global__ __launch_bounds__(256) void k_ln_score(
    const _Float16* __restrict__ X, const float* __restrict__ g,
    const float* __restrict__ bta, const float* __restrict__ Ws,
    const float* __restrict__ bs, float* __restrict__ scores){
  int tid = threadIdx.x, lane = tid & 63, wv = tid >> 6;
  size_t row0 = (size_t)blockIdx.x*32 + wv*8;
  int e0 = lane*8;
  float wv_[8], gv[8], bv[8];
  *(float4*)(wv_ ) = *(const float4*)(Ws + e0);
  *(float4*)(wv_+4) = *(const float4*)(Ws + e0 + 4);
  *(float4*)(gv  ) = *(const float4*)(g + e0);
  *(float4*)(gv+4) = *(const float4*)(g + e0 + 4);
  *(float4*)(bv  ) = *(const float4*)(bta + e0);
  *(float4*)(bv+4) = *(const float4*)(bta + e0 + 4);
  float bsv = bs[0];
  for (int rr = 0; rr < 8; ++rr){
    size_t row = row0 + rr;
    half8 hx = *(const half8*)(X + row*G_ + e0);
    float xv[8];
#pragma unroll
    for (int t = 0; t < 8; ++t) xv[t] = (float)hx[t];
    float s1 = 0.f, s2 = 0.f;
#pragma unroll
    for (int t = 0; t < 8; ++t){ s1 += xv[t]; s2 += xv[t]*xv[t]; }
    s1 = wave_sum_f(s1); s2 = wave_sum_f(s2);
    float mu = s1*(1.f/512.f);
    float var = s2*(1.f/512.f) - mu*mu;
    float rs = rsqrtf(var + 1e-5f);
    float sc = 0.f;
#pragma unroll
    for (int t = 0; t < 8; ++t) sc += ((xv[t]-mu)*rs*gv[t] + bv[t])*wv_[t];
    sc = wave_sum_f(sc);
    if (lane == 0) scores[row] = sc + bsv;
  }
}

// ---------------- K5: softmax over S per batch ------------------------------
__global__ __launch_bounds__(256) void k_softmax(
    const float* __restrict__ scores, float* __restrict__ probs){
  __shared__ float red[4];
  int b = blockIdx.x, tid = threadIdx.x, lane = tid & 63, wv = tid >> 6;
  const float* sp = scores + (size_t)b*S_;
  float mx = -1e30f;
  for (int i = tid; i < S_; i += 256) mx = fmaxf(mx, sp[i]);
  mx = wave_max_f(mx);
  if (lane == 0) red[wv] = mx;
  __syncthreads();
  mx = fmaxf(fmaxf(red[0], red[1]), fmaxf(red[2], red[3]));
  __syncthreads();
  float sum = 0.f;
  for (int i = tid; i < S_; i += 256) sum += __expf(sp[i]-mx);
  sum = wave_sum_f(sum);
  if (lane == 0) red[wv] = sum;
  __syncthreads();
  sum = red[0]+red[1]+red[2]+red[3];
  float inv = 1.f/sum;
  for (int i = tid; i < S_; i += 256)
    probs[(size_t)b*S_ + i] = __expf(sp[i]-mx)*inv;
}

// ---------------- K6: spectrum scatter --------------------------------------
__global__ __launch_bounds__(256) void k_spect(
    const float* __restrict__ peaks, const float* __restrict__ probs,
    float* __restrict__ spect){
  __shared__ float bins[512];
  int b = blockIdx.x, tid = threadIdx.x;
  bins[tid] = 0.f; bins[tid+256] = 0.f;
  __syncthreads();
  for (int i = tid; i < S_*M_; i += 256){
    int s = i >> 3, m = i & 7;
    const float* pk = peaks + (((size_t)b*S_ + s)*M_ + m)*2;
    float mass = pk[0], inten = pk[1];
    float p = probs[(size_t)b*S_ + s];
    int bin = (int)rintf(mass);
    bin = min(max(bin, 0), 511);
    atomicAdd(&bins[bin], inten*p);
  }
  __syncthreads();
  spect[(size_t)b*512 + tid]       = bins[tid];
  spect[(size_t)b*512 + tid + 256] = bins[tid+256];
}

// ---------------- launcher --------------------------------------------------
extern "C" void kernel_launch(void* const* d_in, const int* in_sizes, int n_in,
                              void* d_out, int out_size, void* d_ws, size_t ws_size,
                              hipStream_t stream) {
  const float* vf       = (const float*)d_in[0];
  const float* mask     = (const float*)d_in[1];
  const float* eoh      = (const float*)d_in[2];
  const float* subs     = (const float*)d_in[4];
  const float* peaks    = (const float*)d_in[5];
  const float* ln_sub_g = (const float*)d_in[6];
  const float* ln_sub_b = (const float*)d_in[7];
  const float* W_ih     = (const float*)d_in[8];
  const float* W_hh     = (const float*)d_in[9];
  const float* b_ih     = (const float*)d_in[10];
  const float* b_hh     = (const float*)d_in[11];
  const float* W1       = (const float*)d_in[12];
  const float* b1       = (const float*)d_in[13];
  const float* W2a      = (const float*)d_in[14];
  const float* b2a      = (const float*)d_in[15];
  const float* W2b      = (const float*)d_in[16];
  const float* b2b      = (const float*)d_in[17];
  const float* ln_pre_g = (const float*)d_in[18];
  const float* ln_pre_b = (const float*)d_in[19];
  const float* Ws       = (const float*)d_in[20];
  const float* bs       = (const float*)d_in[21];
  float* out = (float*)d_out;            // [0,8192) spect, [8192,73728) probs
  float* probs_out = out + (size_t)B_*512;

  // workspace carve — total ~155 MB (ws >= ~206 MB proven in round 3)
  char* w = (char*)d_ws;
  float* Pn = (float*)w;         w += (size_t)100*512*4;
  int*   cpk = (int*)w;          w += (size_t)BS_*4;
  float* scores = (float*)w;     w += (size_t)BS_*4;
  _Float16* Wcat = (_Float16*)w; w += (size_t)NG_*KC_*2;
  _Float16* W1h  = (_Float16*)w; w += (size_t)G_*G_*2;
  _Float16* W2ah = (_Float16*)w; w += (size_t)G_*G_*2;
  _Float16* W2bh = (_Float16*)w; w += (size_t)G_*G_*2;
  _Float16* Abuf = (_Float16*)w; w += (size_t)BS_*KC_*2;       // 84 MB
  _Float16* bufh0 = (_Float16*)w;                              // 67 MB (H)
  _Float16* bufh1 = Abuf;        // FF ping-pong reuses A region (84 >= 67 MB)

  k_cvt<<<(G_*G_/4+255)/256, 256, 0, stream>>>(W1,  W1h,  G_*G_);
  k_cvt<<<(G_*G_/4+255)/256, 256, 0, stream>>>(W2a, W2ah, G_*G_);
  k_cvt<<<(G_*G_/4+255)/256, 256, 0, stream>>>(W2b, W2bh, G_*G_);
  k_buildw<<<NG_, 64, 0, stream>>>(W_hh, W_ih, Wcat);
  k_pn<<<2, 256, 0, stream>>>(W_ih, Pn);
  k_prep_mfma<<<dim3(S_/128, B_), 256, 0, stream>>>(vf, mask, eoh, subs,
                                                    ln_sub_g, ln_sub_b, Abuf, cpk);
  k_gru_fused<<<dim3(8, 512), 256, 0, stream>>>(Abuf, Wcat, Pn, b_ih, b_hh,
                                                cpk, bufh0);
  k_gemm<<<dim3(8, 256), 256, 0, stream>>>(bufh0, W1h,  b1,  bufh1);
  k_gemm<<<dim3(8, 256), 256, 0, stream>>>(bufh1, W2ah, b2a, bufh0);
  k_gemm<<<dim3(8, 256), 256, 0, stream>>>(bufh0, W2bh, b2b, bufh1);
  k_ln_score<<<BS_/32, 256, 0, stream>>>(bufh1, ln_pre_g, ln_pre_b, Ws, bs, scores);
  k_softmax<<<B_, 256, 0, stream>>>(scores, probs_out);
  k_spect<<<B_, 256, 0, stream>>>(peaks, probs_out, out);
}

// Round 9
// 556.872 us; speedup vs baseline: 1.0186x; 1.0186x over previous
//
#include <hip/hip_runtime.h>
#include <math.h>

#define B_ 16
#define A_ 32
#define G_ 512
#define S_ 4096
#define M_ 8
#define BS_ 65536
#define NG_ 1536

typedef _Float16 half8 __attribute__((ext_vector_type(8)));
typedef _Float16 half4v __attribute__((ext_vector_type(4)));
typedef _Float16 half2v __attribute__((ext_vector_type(2)));
typedef float floatx4 __attribute__((ext_vector_type(4)));

typedef const __attribute__((address_space(1))) void* gas_t;
typedef __attribute__((address_space(3))) void* las_t;

// ---------------- helpers ----------------
__device__ __forceinline__ float wave_sum_f(float v){
#pragma unroll
  for (int o = 32; o > 0; o >>= 1) v += __shfl_xor(v, o);
  return v;
}
__device__ __forceinline__ float wave_max_f(float v){
#pragma unroll
  for (int o = 32; o > 0; o >>= 1) v = fmaxf(v, __shfl_xor(v, o));
  return v;
}
__device__ __forceinline__ float sigmoidf_(float x){ return 1.f/(1.f+__expf(-x)); }
__device__ __forceinline__ float tanhf_(float x){ return 1.f - 2.f/(__expf(2.f*x)+1.f); }

// ---------------- K0a: fp32 -> fp16 convert (n % 4 == 0) --------------------
__global__ __launch_bounds__(256) void k_cvt(const float* __restrict__ s,
                                             _Float16* __restrict__ d, int n){
  int i = (blockIdx.x*256 + threadIdx.x)*4;
  if (i >= n) return;
  float4 v = *(const float4*)(s+i);
  half4v o; o[0]=(_Float16)v.x; o[1]=(_Float16)v.y; o[2]=(_Float16)v.z; o[3]=(_Float16)v.w;
  *(half4v*)(d+i) = o;
}

// ---------------- K0b: Pt[3][100][512] — transposed prefix tables ----------
// Pt[g][k][d] = prefix-sum over the 20-wide field containing k of
// W_ih[(g*512+d)][k]. Thermometer-OH dot product == sum of 5 such entries.
__global__ __launch_bounds__(256) void k_pt(const float* __restrict__ Wih,
                                            float* __restrict__ Pt){
  int j = blockIdx.x*256 + threadIdx.x;   // j = g*512 + d, 1536 total
  if (j >= 1536) return;
  int g = j >> 9, d = j & 511;
  const float* src = Wih + (size_t)j*100;
  float* dst = Pt + (size_t)g*100*512 + d;
#pragma unroll
  for (int f = 0; f < 5; ++f){
    int off = f*20;
    float run = 0.f;
    for (int k = 0; k < 20; ++k){
      run += src[off + k];
      dst[(size_t)(off + k)*512] = run;
    }
  }
}

// ---------------- K1: MFMA prep — swvs GEMM + LN + counts -------------------
__global__ __launch_bounds__(256) void k_prep_mfma(
    const float* __restrict__ vf, const float* __restrict__ mask,
    const float* __restrict__ eoh, const float* __restrict__ subs,
    const float* __restrict__ ln_g, const float* __restrict__ ln_b,
    _Float16* __restrict__ Abuf, int* __restrict__ cpk){
  __shared__ _Float16 s_mvfT[G_*A_];   // [g][a], masked vf, 32 KB
  __shared__ _Float16 s_sm[128*A_];    // [s][a], raw subs, 8 KB
  __shared__ float s_m[A_];
  __shared__ float s_e[A_*5];
  __shared__ float s_ssum[128];
  __shared__ float s_red1[4][16];
  __shared__ float s_red2[4][16];
  int tid = threadIdx.x;
  int bx = blockIdx.x, b = blockIdx.y;
  int lane = tid & 63, w = tid >> 6;
  int q = lane >> 4, l15 = lane & 15;
  size_t row0 = (size_t)b*S_ + (size_t)bx*128;
  if (tid < A_)   s_m[tid] = mask[b*A_ + tid];
  if (tid < A_*5) s_e[tid] = eoh[b*A_*5 + tid];
  __syncthreads();
  {
    int p = tid & 15, gseg = tid >> 4;
    float mk0 = s_m[2*p], mk1 = s_m[2*p+1];
    const float* v0 = vf + ((size_t)b*A_ + 2*p)*G_ + gseg*32;
    const float* v1 = v0 + G_;
#pragma unroll
    for (int i = 0; i < 32; ++i){
      int g = gseg*32 + i;
      half2v h; h[0] = (_Float16)(v0[i]*mk0); h[1] = (_Float16)(v1[i]*mk1);
      *(half2v*)(s_mvfT + g*A_ + 2*p) = h;
    }
  }
  {
    int s = tid >> 1, hh = tid & 1;
    const float* sp = subs + (row0 + s)*A_ + hh*16;
#pragma unroll
    for (int i = 0; i < 16; i += 2){
      half2v h; h[0] = (_Float16)sp[i]; h[1] = (_Float16)sp[i+1];
      *(half2v*)(s_sm + s*A_ + hh*16 + i) = h;
    }
  }
  __syncthreads();
  if (tid < 128){
    int s = tid;
    float ssum = 0.f, c0=0.f, c1=0.f, c2=0.f, c3=0.f, c4=0.f;
#pragma unroll
    for (int a = 0; a < A_; ++a){
      float v = (float)s_sm[s*A_ + a];
      ssum += v * s_m[a];
      c0 += v * s_e[a*5+0]; c1 += v * s_e[a*5+1]; c2 += v * s_e[a*5+2];
      c3 += v * s_e[a*5+3]; c4 += v * s_e[a*5+4];
    }
    int cc[5];
    cc[0] = min(max((int)(c0+0.5f),0),19); cc[1] = min(max((int)(c1+0.5f),0),19);
    cc[2] = min(max((int)(c2+0.5f),0),19); cc[3] = min(max((int)(c3+0.5f),0),19);
    cc[4] = min(max((int)(c4+0.5f),0),19);
    cpk[row0 + s] = cc[0] | (cc[1]<<6) | (cc[2]<<12) | (cc[3]<<18) | (cc[4]<<24);
    s_ssum[s] = ssum;
  }
  half8 bf[8]; float lng[8], lnb[8];
#pragma unroll
  for (int t = 0; t < 8; ++t){
    int g = w*128 + t*16 + l15;
    bf[t] = *(const half8*)(s_mvfT + g*A_ + q*8);
    lng[t] = ln_g[g]; lnb[t] = ln_b[g];
  }
  __syncthreads();
  for (int gi = 0; gi < 8; ++gi){
    half8 af = *(const half8*)(s_sm + (gi*16 + l15)*A_ + q*8);
    floatx4 c[8];
#pragma unroll
    for (int t = 0; t < 8; ++t){
      floatx4 z = {0.f, 0.f, 0.f, 0.f};
      c[t] = __builtin_amdgcn_mfma_f32_16x16x32_f16(af, bf[t], z, 0, 0, 0);
    }
    float p1[4] = {0.f,0.f,0.f,0.f}, p2[4] = {0.f,0.f,0.f,0.f};
#pragma unroll
    for (int t = 0; t < 8; ++t)
#pragma unroll
      for (int r = 0; r < 4; ++r){ float v = c[t][r]; p1[r] += v; p2[r] += v*v; }
#pragma unroll
    for (int off = 1; off < 16; off <<= 1)
#pragma unroll
      for (int r = 0; r < 4; ++r){
        p1[r] += __shfl_xor(p1[r], off);
        p2[r] += __shfl_xor(p2[r], off);
      }
    if (l15 == 0){
#pragma unroll
      for (int r = 0; r < 4; ++r){ s_red1[w][q*4+r] = p1[r]; s_red2[w][q*4+r] = p2[r]; }
    }
    __syncthreads();
#pragma unroll
    for (int r = 0; r < 4; ++r){
      int sl = gi*16 + q*4 + r;
      int rr = q*4 + r;
      float t1 = s_red1[0][rr] + s_red1[1][rr] + s_red1[2][rr] + s_red1[3][rr];
      float t2 = s_red2[0][rr] + s_red2[1][rr] + s_red2[2][rr] + s_red2[3][rr];
      float inv = 1.f/(s_ssum[sl] + 1e-4f);
      float mu = t1*inv*(1.f/512.f);
      float var = t2*inv*inv*(1.f/512.f) - mu*mu;
      float rs = rsqrtf(var + 1e-5f);
      _Float16* orow = Abuf + (row0 + sl)*G_;
#pragma unroll
      for (int t = 0; t < 8; ++t){
        float o = (c[t][r]*inv - mu)*rs*lng[t] + lnb[t];
        orow[w*128 + t*16 + l15] = (_Float16)o;
      }
    }
    __syncthreads();
  }
}

// ---------------- K2: fused gh GEMM (3 gates) + GRU elementwise -------------
// K=512 (OH removed). grid (8, 512), 512 thr. xcd=bx; mt=bx*64+(by>>3), dt=by&7.
// Block tile 128m x 192n (3 gates x 64 d). Waves 2x4: wave 64m x 48n,
// acc 12 floatx4 = 48 regs. gi for all 3 gates via coalesced prefix tables.
__global__ __launch_bounds__(512) void k_gru_fused(
    const _Float16* __restrict__ Abuf, const _Float16* __restrict__ W16,
    const float* __restrict__ Pt, const float* __restrict__ bih,
    const float* __restrict__ bhh, const int* __restrict__ cpk,
    _Float16* __restrict__ H){
  __shared__ _Float16 smA[128*32];   // 8 KB
  __shared__ _Float16 smB[192*32];   // 12 KB
  int tid = threadIdx.x;
  int lane = tid & 63, wvid = tid >> 6;      // 8 waves
  int wm = wvid & 1, wn = wvid >> 1;         // wm {0,1}, wn {0..3}
  int q = lane >> 4, l15 = lane & 15;
  int mt = blockIdx.x*64 + (blockIdx.y >> 3);
  int dt = blockIdx.y & 7;
  int m0 = mt*128, n0 = dt*64;
  floatx4 acc[3][4] = {};
  int offA[4], offB[3];
#pragma unroll
  for (int i = 0; i < 4; ++i){
    int r = wm*64 + i*16 + l15;
    offA[i] = (r*4 + (q ^ ((r>>2)&3)))*8;
  }
#pragma unroll
  for (int g = 0; g < 3; ++g){
    int rb = g*64 + wn*16 + l15;
    offB[g] = (rb*4 + (q ^ ((rb>>2)&3)))*8;
  }
  // staging: A 8 segs (1/wave); B 12 segs (wave w: seg w; waves 0-3 also 8+w)
  const _Float16* gA;
  {
    int u = wvid*64 + lane;
    int r = u >> 2, c = (u & 3) ^ ((r >> 2) & 3);
    gA = Abuf + (size_t)(m0 + r)*G_ + c*8;
  }
  const _Float16* gB0;
  {
    int u = wvid*64 + lane;
    int rb = u >> 2, c = (u & 3) ^ ((rb >> 2) & 3);
    int grow = (rb >> 6)*512 + n0 + (rb & 63);
    gB0 = W16 + (size_t)grow*G_ + c*8;
  }
  const _Float16* gB1 = nullptr;
  if (wvid < 4){
    int u = (8 + wvid)*64 + lane;
    int rb = u >> 2, c = (u & 3) ^ ((rb >> 2) & 3);
    int grow = (rb >> 6)*512 + n0 + (rb & 63);
    gB1 = W16 + (size_t)grow*G_ + c*8;
  }
  for (int kc = 0; kc < G_; kc += 32){
    __builtin_amdgcn_global_load_lds((gas_t)(gA + kc), (las_t)(smA + wvid*512), 16, 0, 0);
    __builtin_amdgcn_global_load_lds((gas_t)(gB0 + kc), (las_t)(smB + wvid*512), 16, 0, 0);
    if (wvid < 4)
      __builtin_amdgcn_global_load_lds((gas_t)(gB1 + kc), (las_t)(smB + (8+wvid)*512), 16, 0, 0);
    __syncthreads();
    half8 af[4], bfv[3];
#pragma unroll
    for (int i = 0; i < 4; ++i) af[i] = *(const half8*)(smA + offA[i]);
#pragma unroll
    for (int g = 0; g < 3; ++g) bfv[g] = *(const half8*)(smB + offB[g]);
#pragma unroll
    for (int g = 0; g < 3; ++g)
#pragma unroll
      for (int i = 0; i < 4; ++i)
        acc[g][i] = __builtin_amdgcn_mfma_f32_16x16x32_f16(af[i], bfv[g], acc[g][i], 0, 0, 0);
    __syncthreads();
  }
  // epilogue: one d per lane; 3 prefix tables, coalesced in d
  int d = n0 + wn*16 + l15;
  const float* Pr = Pt + d;
  const float* Pz = Pt + 100*512 + d;
  const float* Pn = Pt + 200*512 + d;
  float br  = bih[d] + bhh[d];
  float bz  = bih[512+d] + bhh[512+d];
  float bnh = bhh[1024+d];
  float bni = bih[1024+d];
#pragma unroll
  for (int i = 0; i < 4; ++i){
#pragma unroll
    for (int r = 0; r < 4; ++r){
      int m = m0 + wm*64 + i*16 + q*4 + r;
      int cp = cpk[m];
      int k0 = ((cp      ) & 63)*512;
      int k1 = (((cp >> 6 ) & 63) + 20)*512;
      int k2 = (((cp >> 12) & 63) + 40)*512;
      int k3 = (((cp >> 18) & 63) + 60)*512;
      int k4 = (((cp >> 24) & 63) + 80)*512;
      float sr = Pr[k0]+Pr[k1]+Pr[k2]+Pr[k3]+Pr[k4];
      float sz = Pz[k0]+Pz[k1]+Pz[k2]+Pz[k3]+Pz[k4];
      float sn = Pn[k0]+Pn[k1]+Pn[k2]+Pn[k3]+Pn[k4];
      float gr = acc[0][i][r] + br + sr;
      float gz = acc[1][i][r] + bz + sz;
      float hn = acc[2][i][r] + bnh;
      float in_ = bni + sn;
      float rrv = sigmoidf_(gr);
      float zz  = sigmoidf_(gz);
      float nn  = tanhf_(in_ + rrv*hn);
      float hp = (float)Abuf[(size_t)m*G_ + d];
      H[(size_t)m*G_ + d] = (_Float16)((1.f-zz)*nn + zz*hp);
    }
  }
}

// ---------------- K3: FF fp16 MFMA GEMM  Out = relu(A @ W^T + bias) ---------
// K=512, N=512. grid (8, 256): xcd=bx; mt = bx*64 + (by>>2), nt = by&3.
__global__ __launch_bounds__(256) void k_gemm(
    const _Float16* __restrict__ A, const _Float16* __restrict__ W,
    const float* __restrict__ bias, _Float16* __restrict__ Out){
  __shared__ _Float16 smA[128*32];
  __shared__ _Float16 smB[128*32];
  int tid = threadIdx.x;
  int lane = tid & 63, wvid = tid >> 6;
  int wm = wvid & 1, wn = wvid >> 1;
  int q = lane >> 4, l15 = lane & 15;
  int mt = blockIdx.x*64 + (blockIdx.y >> 2);
  int nt = blockIdx.y & 3;
  int m0 = mt*128, n0 = nt*128;
  floatx4 acc[4][4] = {};
  int offA[4], offB[4];
#pragma unroll
  for (int i = 0; i < 4; ++i){
    int r = wm*64 + i*16 + l15;
    offA[i] = (r*4 + (q ^ ((r>>2)&3)))*8;
    int rb = wn*64 + i*16 + l15;
    offB[i] = (rb*4 + (q ^ ((rb>>2)&3)))*8;
  }
  int uA[2];
  const _Float16 *gA[2], *gB[2];
#pragma unroll
  for (int t = 0; t < 2; ++t){
    int seg = wvid*2 + t;
    int u = seg*64 + lane;
    int r = u >> 2, c = (u & 3) ^ ((r >> 2) & 3);
    uA[t] = seg;
    gA[t] = A + (size_t)(m0 + r)*G_ + c*8;
    gB[t] = W + (size_t)(n0 + r)*G_ + c*8;
  }
  for (int kc = 0; kc < G_; kc += 32){
#pragma unroll
    for (int t = 0; t < 2; ++t){
      __builtin_amdgcn_global_load_lds((gas_t)(gA[t] + kc), (las_t)(smA + uA[t]*512), 16, 0, 0);
      __builtin_amdgcn_global_load_lds((gas_t)(gB[t] + kc), (las_t)(smB + uA[t]*512), 16, 0, 0);
    }
    __syncthreads();
    half8 af[4], bfv[4];
#pragma unroll
    for (int i = 0; i < 4; ++i) af[i] = *(const half8*)(smA + offA[i]);
#pragma unroll
    for (int j = 0; j < 4; ++j) bfv[j] = *(const half8*)(smB + offB[j]);
#pragma unroll
    for (int i = 0; i < 4; ++i)
#pragma unroll
      for (int j = 0; j < 4; ++j)
        acc[i][j] = __builtin_amdgcn_mfma_f32_16x16x32_f16(af[i], bfv[j], acc[i][j], 0, 0, 0);
    __syncthreads();
  }
#pragma unroll
  for (int j = 0; j < 4; ++j){
    int n = n0 + wn*64 + j*16 + l15;
    float bv = bias[n];
#pragma unroll
    for (int i = 0; i < 4; ++i){
#pragma unroll
      for (int r = 0; r < 4; ++r){
        int m = m0 + wm*64 + i*16 + q*4 + r;
        Out[(size_t)m*G_ + n] = (_Float16)fmaxf(acc[i][j][r] + bv, 0.f);
      }
    }
  }
}

// ---------------- K4: final LN + score (fp16 in, fp32 out) ------------------
__global__ __launch_bounds__(256) void k_ln_score(
    const _Float16* __restrict__ X, const float* __restrict__ g,
    const float* __restrict__ bta, const float* __restrict__ Ws,
    const float* __restrict__ bs, float* __restrict__ scores){
  int tid = threadIdx.x, lane = tid & 63, wv = tid >> 6;
  size_t row0 = (size_t)blockIdx.x*32 + wv*8;
  int e0 = lane*8;
  float wv_[8], gv[8], bv[8];
  *(float4*)(wv_ ) = *(const float4*)(Ws + e0);
  *(float4*)(wv_+4) = *(const float4*)(Ws + e0 + 4);
  *(float4*)(gv  ) = *(const float4*)(g + e0);
  *(float4*)(gv+4) = *(const float4*)(g + e0 + 4);
  *(float4*)(bv  ) = *(const float4*)(bta + e0);
  *(float4*)(bv+4) = *(const float4*)(bta + e0 + 4);
  float bsv = bs[0];
  for (int rr = 0; rr < 8; ++rr){
    size_t row = row0 + rr;
    half8 hx = *(const half8*)(X + row*G_ + e0);
    float xv[8];
#pragma unroll
    for (int t = 0; t < 8; ++t) xv[t] = (float)hx[t];
    float s1 = 0.f, s2 = 0.f;
#pragma unroll
    for (int t = 0; t < 8; ++t){ s1 += xv[t]; s2 += xv[t]*xv[t]; }
    s1 = wave_sum_f(s1); s2 = wave_sum_f(s2);
    float mu = s1*(1.f/512.f);
    float var = s2*(1.f/512.f) - mu*mu;
    float rs = rsqrtf(var + 1e-5f);
    float sc = 0.f;
#pragma unroll
    for (int t = 0; t < 8; ++t) sc += ((xv[t]-mu)*rs*gv[t] + bv[t])*wv_[t];
    sc = wave_sum_f(sc);
    if (lane == 0) scores[row] = sc + bsv;
  }
}

// ---------------- K5: softmax over S per batch ------------------------------
__global__ __launch_bounds__(256) void k_softmax(
    const float* __restrict__ scores, float* __restrict__ probs){
  __shared__ float red[4];
  int b = blockIdx.x, tid = threadIdx.x, lane = tid & 63, wv = tid >> 6;
  const float* sp = scores + (size_t)b*S_;
  float mx = -1e30f;
  for (int i = tid; i < S_; i += 256) mx = fmaxf(mx, sp[i]);
  mx = wave_max_f(mx);
  if (lane == 0) red[wv] = mx;
  __syncthreads();
  mx = fmaxf(fmaxf(red[0], red[1]), fmaxf(red[2], red[3]));
  __syncthreads();
  float sum = 0.f;
  for (int i = tid; i < S_; i += 256) sum += __expf(sp[i]-mx);
  sum = wave_sum_f(sum);
  if (lane == 0) red[wv] = sum;
  __syncthreads();
  sum = red[0]+red[1]+red[2]+red[3];
  float inv = 1.f/sum;
  for (int i = tid; i < S_; i += 256)
    probs[(size_t)b*S_ + i] = __expf(sp[i]-mx)*inv;
}

// ---------------- K6: spectrum scatter --------------------------------------
__global__ __launch_bounds__(256) void k_spect(
    const float* __restrict__ peaks, const float* __restrict__ probs,
    float* __restrict__ spect){
  __shared__ float bins[512];
  int b = blockIdx.x, tid = threadIdx.x;
  bins[tid] = 0.f; bins[tid+256] = 0.f;
  __syncthreads();
  for (int i = tid; i < S_*M_; i += 256){
    int s = i >> 3, m = i & 7;
    const float* pk = peaks + (((size_t)b*S_ + s)*M_ + m)*2;
    float mass = pk[0], inten = pk[1];
    float p = probs[(size_t)b*S_ + s];
    int bin = (int)rintf(mass);
    bin = min(max(bin, 0), 511);
    atomicAdd(&bins[bin], inten*p);
  }
  __syncthreads();
  spect[(size_t)b*512 + tid]       = bins[tid];
  spect[(size_t)b*512 + tid + 256] = bins[tid+256];
}

// ---------------- launcher --------------------------------------------------
extern "C" void kernel_launch(void* const* d_in, const int* in_sizes, int n_in,
                              void* d_out, int out_size, void* d_ws, size_t ws_size,
                              hipStream_t stream) {
  const float* vf       = (const float*)d_in[0];
  const float* mask     = (const float*)d_in[1];
  const float* eoh      = (const float*)d_in[2];
  const float* subs     = (const float*)d_in[4];
  const float* peaks    = (const float*)d_in[5];
  const float* ln_sub_g = (const float*)d_in[6];
  const float* ln_sub_b = (const float*)d_in[7];
  const float* W_ih     = (const float*)d_in[8];
  const float* W_hh     = (const float*)d_in[9];
  const float* b_ih     = (const float*)d_in[10];
  const float* b_hh     = (const float*)d_in[11];
  const float* W1       = (const float*)d_in[12];
  const float* b1       = (const float*)d_in[13];
  const float* W2a      = (const float*)d_in[14];
  const float* b2a      = (const float*)d_in[15];
  const float* W2b      = (const float*)d_in[16];
  const float* b2b      = (const float*)d_in[17];
  const float* ln_pre_g = (const float*)d_in[18];
  const float* ln_pre_b = (const float*)d_in[19];
  const float* Ws       = (const float*)d_in[20];
  const float* bs       = (const float*)d_in[21];
  float* out = (float*)d_out;            // [0,8192) spect, [8192,73728) probs
  float* probs_out = out + (size_t)B_*512;

  // workspace carve — ~140 MB (ws >= ~206 MB proven)
  char* w = (char*)d_ws;
  float* Pt = (float*)w;         w += (size_t)3*100*512*4;     // 614400
  int*   cpk = (int*)w;          w += (size_t)BS_*4;
  float* scores = (float*)w;     w += (size_t)BS_*4;
  _Float16* W3h  = (_Float16*)w; w += (size_t)NG_*G_*2;        // 1.57 MB
  _Float16* W1h  = (_Float16*)w; w += (size_t)G_*G_*2;
  _Float16* W2ah = (_Float16*)w; w += (size_t)G_*G_*2;
  _Float16* W2bh = (_Float16*)w; w += (size_t)G_*G_*2;
  _Float16* Abuf = (_Float16*)w; w += (size_t)BS_*G_*2;        // 67 MB
  _Float16* bufh0 = (_Float16*)w;                              // 67 MB (H)
  _Float16* bufh1 = Abuf;        // FF ping-pong reuses A region

  k_cvt<<<(NG_*G_/4+255)/256, 256, 0, stream>>>(W_hh, W3h, NG_*G_);
  k_cvt<<<(G_*G_/4+255)/256, 256, 0, stream>>>(W1,  W1h,  G_*G_);
  k_cvt<<<(G_*G_/4+255)/256, 256, 0, stream>>>(W2a, W2ah, G_*G_);
  k_cvt<<<(G_*G_/4+255)/256, 256, 0, stream>>>(W2b, W2bh, G_*G_);
  k_pt<<<6, 256, 0, stream>>>(W_ih, Pt);
  k_prep_mfma<<<dim3(S_/128, B_), 256, 0, stream>>>(vf, mask, eoh, subs,
                                                    ln_sub_g, ln_sub_b, Abuf, cpk);
  k_gru_fused<<<dim3(8, 512), 512, 0, stream>>>(Abuf, W3h, Pt, b_ih, b_hh,
                                                cpk, bufh0);
  k_gemm<<<dim3(8, 256), 256, 0, stream>>>(bufh0, W1h,  b1,  bufh1);
  k_gemm<<<dim3(8, 256), 256, 0, stream>>>(bufh1, W2ah, b2a, bufh0);
  k_gemm<<<dim3(8, 256), 256, 0, stream>>>(bufh0, W2bh, b2b, bufh1);
  k_ln_score<<<BS_/32, 256, 0, stream>>>(bufh1, ln_pre_g, ln_pre_b, Ws, bs, scores);
  k_softmax<<<B_, 256, 0, stream>>>(scores, probs_out);
  k_spect<<<B_, 256, 0, stream>>>(peaks, probs_out, out);
}

// Round 10
// 522.798 us; speedup vs baseline: 1.0850x; 1.0652x over previous
//
#include <hip/hip_runtime.h>
#include <math.h>

#define B_ 16
#define A_ 32
#define G_ 512
#define S_ 4096
#define M_ 8
#define BS_ 65536
#define KC_ 640      // concat K: 512 normed + 100 OH + 28 pad
#define NG_ 1536

typedef _Float16 half8 __attribute__((ext_vector_type(8)));
typedef _Float16 half4v __attribute__((ext_vector_type(4)));
typedef _Float16 half2v __attribute__((ext_vector_type(2)));
typedef float floatx4 __attribute__((ext_vector_type(4)));

typedef const __attribute__((address_space(1))) void* gas_t;
typedef __attribute__((address_space(3))) void* las_t;

// ---------------- helpers ----------------
__device__ __forceinline__ float wave_sum_f(float v){
#pragma unroll
  for (int o = 32; o > 0; o >>= 1) v += __shfl_xor(v, o);
  return v;
}
__device__ __forceinline__ float wave_max_f(float v){
#pragma unroll
  for (int o = 32; o > 0; o >>= 1) v = fmaxf(v, __shfl_xor(v, o));
  return v;
}
__device__ __forceinline__ float sigmoidf_(float x){ return 1.f/(1.f+__expf(-x)); }
__device__ __forceinline__ float tanhf_(float x){ return 1.f - 2.f/(__expf(2.f*x)+1.f); }

// ---------------- K0a: fp32 -> fp16 convert (n % 4 == 0) --------------------
__global__ __launch_bounds__(256) void k_cvt(const float* __restrict__ s,
                                             _Float16* __restrict__ d, int n){
  int i = (blockIdx.x*256 + threadIdx.x)*4;
  if (i >= n) return;
  float4 v = *(const float4*)(s+i);
  half4v o; o[0]=(_Float16)v.x; o[1]=(_Float16)v.y; o[2]=(_Float16)v.z; o[3]=(_Float16)v.w;
  *(half4v*)(d+i) = o;
}

// ---------------- K0b: build Wcat[1536][640] = [W_hh | W_ih | 0] ------------
// ALL gate rows get W_ih in cols [512,612) (n-gate i_n handled by split acc).
__global__ __launch_bounds__(64) void k_buildw(const float* __restrict__ Whh,
                                               const float* __restrict__ Wih,
                                               _Float16* __restrict__ Wcat){
  int j = blockIdx.x;
  for (int p = threadIdx.x; p < KC_; p += 64){
    float v = 0.f;
    if (p < 512) v = Whh[(size_t)j*512 + p];
    else if (p < 612) v = Wih[(size_t)j*100 + (p - 512)];
    Wcat[(size_t)j*KC_ + p] = (_Float16)v;
  }
}

// ---------------- K1: MFMA prep — swvs GEMM + LN + counts + OH --------------
__global__ __launch_bounds__(256) void k_prep_mfma(
    const float* __restrict__ vf, const float* __restrict__ mask,
    const float* __restrict__ eoh, const float* __restrict__ subs,
    const float* __restrict__ ln_g, const float* __restrict__ ln_b,
    _Float16* __restrict__ Abuf){
  __shared__ _Float16 s_mvfT[G_*A_];   // [g][a], masked vf, 32 KB
  __shared__ _Float16 s_sm[128*A_];    // [s][a], raw subs, 8 KB
  __shared__ float s_m[A_];
  __shared__ float s_e[A_*5];
  __shared__ float s_ssum[128];
  __shared__ float s_red1[4][16];
  __shared__ float s_red2[4][16];
  int tid = threadIdx.x;
  int bx = blockIdx.x, b = blockIdx.y;
  int lane = tid & 63, w = tid >> 6;
  int q = lane >> 4, l15 = lane & 15;
  size_t row0 = (size_t)b*S_ + (size_t)bx*128;
  if (tid < A_)   s_m[tid] = mask[b*A_ + tid];
  if (tid < A_*5) s_e[tid] = eoh[b*A_*5 + tid];
  __syncthreads();
  {
    int p = tid & 15, gseg = tid >> 4;
    float mk0 = s_m[2*p], mk1 = s_m[2*p+1];
    const float* v0 = vf + ((size_t)b*A_ + 2*p)*G_ + gseg*32;
    const float* v1 = v0 + G_;
#pragma unroll
    for (int i = 0; i < 32; ++i){
      int g = gseg*32 + i;
      half2v h; h[0] = (_Float16)(v0[i]*mk0); h[1] = (_Float16)(v1[i]*mk1);
      *(half2v*)(s_mvfT + g*A_ + 2*p) = h;
    }
  }
  {
    int s = tid >> 1, hh = tid & 1;
    const float* sp = subs + (row0 + s)*A_ + hh*16;
#pragma unroll
    for (int i = 0; i < 16; i += 2){
      half2v h; h[0] = (_Float16)sp[i]; h[1] = (_Float16)sp[i+1];
      *(half2v*)(s_sm + s*A_ + hh*16 + i) = h;
    }
  }
  __syncthreads();
  if (tid < 128){
    int s = tid;
    float ssum = 0.f, c0=0.f, c1=0.f, c2=0.f, c3=0.f, c4=0.f;
#pragma unroll
    for (int a = 0; a < A_; ++a){
      float v = (float)s_sm[s*A_ + a];
      ssum += v * s_m[a];
      c0 += v * s_e[a*5+0]; c1 += v * s_e[a*5+1]; c2 += v * s_e[a*5+2];
      c3 += v * s_e[a*5+3]; c4 += v * s_e[a*5+4];
    }
    int cc[5];
    cc[0] = min(max((int)(c0+0.5f),0),19); cc[1] = min(max((int)(c1+0.5f),0),19);
    cc[2] = min(max((int)(c2+0.5f),0),19); cc[3] = min(max((int)(c3+0.5f),0),19);
    cc[4] = min(max((int)(c4+0.5f),0),19);
    s_ssum[s] = ssum;
    _Float16* dst = Abuf + (row0 + s)*KC_ + 512;
#pragma unroll
    for (int t = 0; t < 16; ++t){
      half8 hv;
#pragma unroll
      for (int u = 0; u < 8; ++u){
        int k = t*8 + u;
        float v = 0.f;
        if (k < 100){ int f = k/20, l = k - f*20; v = (l <= cc[f]) ? 1.f : 0.f; }
        hv[u] = (_Float16)v;
      }
      *(half8*)(dst + t*8) = hv;
    }
  }
  half8 bf[8]; float lng[8], lnb[8];
#pragma unroll
  for (int t = 0; t < 8; ++t){
    int g = w*128 + t*16 + l15;
    bf[t] = *(const half8*)(s_mvfT + g*A_ + q*8);
    lng[t] = ln_g[g]; lnb[t] = ln_b[g];
  }
  __syncthreads();
  for (int gi = 0; gi < 8; ++gi){
    half8 af = *(const half8*)(s_sm + (gi*16 + l15)*A_ + q*8);
    floatx4 c[8];
#pragma unroll
    for (int t = 0; t < 8; ++t){
      floatx4 z = {0.f, 0.f, 0.f, 0.f};
      c[t] = __builtin_amdgcn_mfma_f32_16x16x32_f16(af, bf[t], z, 0, 0, 0);
    }
    float p1[4] = {0.f,0.f,0.f,0.f}, p2[4] = {0.f,0.f,0.f,0.f};
#pragma unroll
    for (int t = 0; t < 8; ++t)
#pragma unroll
      for (int r = 0; r < 4; ++r){ float v = c[t][r]; p1[r] += v; p2[r] += v*v; }
#pragma unroll
    for (int off = 1; off < 16; off <<= 1)
#pragma unroll
      for (int r = 0; r < 4; ++r){
        p1[r] += __shfl_xor(p1[r], off);
        p2[r] += __shfl_xor(p2[r], off);
      }
    if (l15 == 0){
#pragma unroll
      for (int r = 0; r < 4; ++r){ s_red1[w][q*4+r] = p1[r]; s_red2[w][q*4+r] = p2[r]; }
    }
    __syncthreads();
#pragma unroll
    for (int r = 0; r < 4; ++r){
      int sl = gi*16 + q*4 + r;
      int rr = q*4 + r;
      float t1 = s_red1[0][rr] + s_red1[1][rr] + s_red1[2][rr] + s_red1[3][rr];
      float t2 = s_red2[0][rr] + s_red2[1][rr] + s_red2[2][rr] + s_red2[3][rr];
      float inv = 1.f/(s_ssum[sl] + 1e-4f);
      float mu = t1*inv*(1.f/512.f);
      float var = t2*inv*inv*(1.f/512.f) - mu*mu;
      float rs = rsqrtf(var + 1e-5f);
      _Float16* orow = Abuf + (row0 + sl)*KC_;
#pragma unroll
      for (int t = 0; t < 8; ++t){
        float o = (c[t][r]*inv - mu)*rs*lng[t] + lnb[t];
        orow[w*128 + t*16 + l15] = (_Float16)o;
      }
    }
    __syncthreads();
  }
}

// ---------------- K2: fused (gh+gi) GEMM (3 gates) + GRU elementwise --------
// K=640: kc<512 accumulates h-part (acc[0..2]); kc>=512 accumulates the OH
// i-part: r,z keep folding into acc[0..1]; the n-gate i_n goes to accNI.
// grid (8, 512), 512 thr. xcd=bx; mt=bx*64+(by>>3), dt=by&7.
// Block tile 128m x 192n. Waves 2x4: wave 64m x 48n. acc 64 f32.
__global__ __launch_bounds__(512) void k_gru_fused(
    const _Float16* __restrict__ Abuf, const _Float16* __restrict__ Wcat,
    const float* __restrict__ bih, const float* __restrict__ bhh,
    _Float16* __restrict__ H){
  __shared__ _Float16 smA[128*32];   // 8 KB
  __shared__ _Float16 smB[192*32];   // 12 KB
  int tid = threadIdx.x;
  int lane = tid & 63, wvid = tid >> 6;      // 8 waves
  int wm = wvid & 1, wn = wvid >> 1;         // wm {0,1}, wn {0..3}
  int q = lane >> 4, l15 = lane & 15;
  int mt = blockIdx.x*64 + (blockIdx.y >> 3);
  int dt = blockIdx.y & 7;
  int m0 = mt*128, n0 = dt*64;
  floatx4 acc[3][4] = {};
  floatx4 accNI[4] = {};
  int offA[4], offB[3];
#pragma unroll
  for (int i = 0; i < 4; ++i){
    int r = wm*64 + i*16 + l15;
    offA[i] = (r*4 + (q ^ ((r>>2)&3)))*8;
  }
#pragma unroll
  for (int g = 0; g < 3; ++g){
    int rb = g*64 + wn*16 + l15;
    offB[g] = (rb*4 + (q ^ ((rb>>2)&3)))*8;
  }
  // staging: A 8 segs (1/wave); B 12 segs (wave w: seg w; waves 0-3 also 8+w)
  const _Float16* gA;
  {
    int u = wvid*64 + lane;
    int r = u >> 2, c = (u & 3) ^ ((r >> 2) & 3);
    gA = Abuf + (size_t)(m0 + r)*KC_ + c*8;
  }
  const _Float16* gB0;
  {
    int u = wvid*64 + lane;
    int rb = u >> 2, c = (u & 3) ^ ((rb >> 2) & 3);
    int grow = (rb >> 6)*512 + n0 + (rb & 63);
    gB0 = Wcat + (size_t)grow*KC_ + c*8;
  }
  const _Float16* gB1 = nullptr;
  if (wvid < 4){
    int u = (8 + wvid)*64 + lane;
    int rb = u >> 2, c = (u & 3) ^ ((rb >> 2) & 3);
    int grow = (rb >> 6)*512 + n0 + (rb & 63);
    gB1 = Wcat + (size_t)grow*KC_ + c*8;
  }
  // phase 1: h-part (kc < 512)
  for (int kc = 0; kc < 512; kc += 32){
    __builtin_amdgcn_global_load_lds((gas_t)(gA + kc), (las_t)(smA + wvid*512), 16, 0, 0);
    __builtin_amdgcn_global_load_lds((gas_t)(gB0 + kc), (las_t)(smB + wvid*512), 16, 0, 0);
    if (wvid < 4)
      __builtin_amdgcn_global_load_lds((gas_t)(gB1 + kc), (las_t)(smB + (8+wvid)*512), 16, 0, 0);
    __syncthreads();
    half8 af[4], bfv[3];
#pragma unroll
    for (int i = 0; i < 4; ++i) af[i] = *(const half8*)(smA + offA[i]);
#pragma unroll
    for (int g = 0; g < 3; ++g) bfv[g] = *(const half8*)(smB + offB[g]);
#pragma unroll
    for (int g = 0; g < 3; ++g)
#pragma unroll
      for (int i = 0; i < 4; ++i)
        acc[g][i] = __builtin_amdgcn_mfma_f32_16x16x32_f16(af[i], bfv[g], acc[g][i], 0, 0, 0);
    __syncthreads();
  }
  // phase 2: OH i-part (kc >= 512): n-gate into accNI
  for (int kc = 512; kc < KC_; kc += 32){
    __builtin_amdgcn_global_load_lds((gas_t)(gA + kc), (las_t)(smA + wvid*512), 16, 0, 0);
    __builtin_amdgcn_global_load_lds((gas_t)(gB0 + kc), (las_t)(smB + wvid*512), 16, 0, 0);
    if (wvid < 4)
      __builtin_amdgcn_global_load_lds((gas_t)(gB1 + kc), (las_t)(smB + (8+wvid)*512), 16, 0, 0);
    __syncthreads();
    half8 af[4], bfv[3];
#pragma unroll
    for (int i = 0; i < 4; ++i) af[i] = *(const half8*)(smA + offA[i]);
#pragma unroll
    for (int g = 0; g < 3; ++g) bfv[g] = *(const half8*)(smB + offB[g]);
#pragma unroll
    for (int i = 0; i < 4; ++i){
      acc[0][i] = __builtin_amdgcn_mfma_f32_16x16x32_f16(af[i], bfv[0], acc[0][i], 0, 0, 0);
      acc[1][i] = __builtin_amdgcn_mfma_f32_16x16x32_f16(af[i], bfv[1], acc[1][i], 0, 0, 0);
      accNI[i]  = __builtin_amdgcn_mfma_f32_16x16x32_f16(af[i], bfv[2], accNI[i], 0, 0, 0);
    }
    __syncthreads();
  }
  // epilogue: pure elementwise — no table gathers
  int d = n0 + wn*16 + l15;
  float br  = bih[d] + bhh[d];
  float bz  = bih[512+d] + bhh[512+d];
  float bnh = bhh[1024+d];
  float bni = bih[1024+d];
#pragma unroll
  for (int i = 0; i < 4; ++i){
#pragma unroll
    for (int r = 0; r < 4; ++r){
      int m = m0 + wm*64 + i*16 + q*4 + r;
      float gr  = acc[0][i][r] + br;
      float gz  = acc[1][i][r] + bz;
      float hn  = acc[2][i][r] + bnh;
      float in_ = accNI[i][r] + bni;
      float rrv = sigmoidf_(gr);
      float zz  = sigmoidf_(gz);
      float nn  = tanhf_(in_ + rrv*hn);
      float hp  = (float)Abuf[(size_t)m*KC_ + d];
      H[(size_t)m*G_ + d] = (_Float16)((1.f-zz)*nn + zz*hp);
    }
  }
}

// ---------------- K3: FF fp16 MFMA GEMM  Out = relu(A @ W^T + bias) ---------
// K=512, N=512. grid (8, 256): xcd=bx; mt = bx*64 + (by>>2), nt = by&3.
__global__ __launch_bounds__(256) void k_gemm(
    const _Float16* __restrict__ A, const _Float16* __restrict__ W,
    const float* __restrict__ bias, _Float16* __restrict__ Out){
  __shared__ _Float16 smA[128*32];
  __shared__ _Float16 smB[128*32];
  int tid = threadIdx.x;
  int lane = tid & 63, wvid = tid >> 6;
  int wm = wvid & 1, wn = wvid >> 1;
  int q = lane >> 4, l15 = lane & 15;
  int mt = blockIdx.x*64 + (blockIdx.y >> 2);
  int nt = blockIdx.y & 3;
  int m0 = mt*128, n0 = nt*128;
  floatx4 acc[4][4] = {};
  int offA[4], offB[4];
#pragma unroll
  for (int i = 0; i < 4; ++i){
    int r = wm*64 + i*16 + l15;
    offA[i] = (r*4 + (q ^ ((r>>2)&3)))*8;
    int rb = wn*64 + i*16 + l15;
    offB[i] = (rb*4 + (q ^ ((rb>>2)&3)))*8;
  }
  int uA[2];
  const _Float16 *gA[2], *gB[2];
#pragma unroll
  for (int t = 0; t < 2; ++t){
    int seg = wvid*2 + t;
    int u = seg*64 + lane;
    int r = u >> 2, c = (u & 3) ^ ((r >> 2) & 3);
    uA[t] = seg;
    gA[t] = A + (size_t)(m0 + r)*G_ + c*8;
    gB[t] = W + (size_t)(n0 + r)*G_ + c*8;
  }
  for (int kc = 0; kc < G_; kc += 32){
#pragma unroll
    for (int t = 0; t < 2; ++t){
      __builtin_amdgcn_global_load_lds((gas_t)(gA[t] + kc), (las_t)(smA + uA[t]*512), 16, 0, 0);
      __builtin_amdgcn_global_load_lds((gas_t)(gB[t] + kc), (las_t)(smB + uA[t]*512), 16, 0, 0);
    }
    __syncthreads();
    half8 af[4], bfv[4];
#pragma unroll
    for (int i = 0; i < 4; ++i) af[i] = *(const half8*)(smA + offA[i]);
#pragma unroll
    for (int j = 0; j < 4; ++j) bfv[j] = *(const half8*)(smB + offB[j]);
#pragma unroll
    for (int i = 0; i < 4; ++i)
#pragma unroll
      for (int j = 0; j < 4; ++j)
        acc[i][j] = __builtin_amdgcn_mfma_f32_16x16x32_f16(af[i], bfv[j], acc[i][j], 0, 0, 0);
    __syncthreads();
  }
#pragma unroll
  for (int j = 0; j < 4; ++j){
    int n = n0 + wn*64 + j*16 + l15;
    float bv = bias[n];
#pragma unroll
    for (int i = 0; i < 4; ++i){
#pragma unroll
      for (int r = 0; r < 4; ++r){
        int m = m0 + wm*64 + i*16 + q*4 + r;
        Out[(size_t)m*G_ + n] = (_Float16)fmaxf(acc[i][j][r] + bv, 0.f);
      }
    }
  }
}

// ---------------- K4: final LN + score (fp16 in, fp32 out) ------------------
__global__ __launch_bounds__(256) void k_ln_score(
    const _Float16* __restrict__ X, const float* __restrict__ g,
    const float* __restrict__ bta, const float* __restrict__ Ws,
    const float* __restrict__ bs, float* __restrict__ scores){
  int tid = threadIdx.x, lane = tid & 63, wv = tid >> 6;
  size_t row0 = (size_t)blockIdx.x*32 + wv*8;
  int e0 = lane*8;
  float wv_[8], gv[8], bv[8];
  *(float4*)(wv_ ) = *(const float4*)(Ws + e0);
  *(float4*)(wv_+4) = *(const float4*)(Ws + e0 + 4);
  *(float4*)(gv  ) = *(const float4*)(g + e0);
  *(float4*)(gv+4) = *(const float4*)(g + e0 + 4);
  *(float4*)(bv  ) = *(const float4*)(bta + e0);
  *(float4*)(bv+4) = *(const float4*)(bta + e0 + 4);
  float bsv = bs[0];
  for (int rr = 0; rr < 8; ++rr){
    size_t row = row0 + rr;
    half8 hx = *(const half8*)(X + row*G_ + e0);
    float xv[8];
#pragma unroll
    for (int t = 0; t < 8; ++t) xv[t] = (float)hx[t];
    float s1 = 0.f, s2 = 0.f;
#pragma unroll
    for (int t = 0; t < 8; ++t){ s1 += xv[t]; s2 += xv[t]*xv[t]; }
    s1 = wave_sum_f(s1); s2 = wave_sum_f(s2);
    float mu = s1*(1.f/512.f);
    float var = s2*(1.f/512.f) - mu*mu;
    float rs = rsqrtf(var + 1e-5f);
    float sc = 0.f;
#pragma unroll
    for (int t = 0; t < 8; ++t) sc += ((xv[t]-mu)*rs*gv[t] + bv[t])*wv_[t];
    sc = wave_sum_f(sc);
    if (lane == 0) scores[row] = sc + bsv;
  }
}

// ---------------- K5: softmax over S per batch ------------------------------
__global__ __launch_bounds__(256) void k_softmax(
    const float* __restrict__ scores, float* __restrict__ probs){
  __shared__ float red[4];
  int b = blockIdx.x, tid = threadIdx.x, lane = tid & 63, wv = tid >> 6;
  const float* sp = scores + (size_t)b*S_;
  float mx = -1e30f;
  for (int i = tid; i < S_; i += 256) mx = fmaxf(mx, sp[i]);
  mx = wave_max_f(mx);
  if (lane == 0) red[wv] = mx;
  __syncthreads();
  mx = fmaxf(fmaxf(red[0], red[1]), fmaxf(red[2], red[3]));
  __syncthreads();
  float sum = 0.f;
  for (int i = tid; i < S_; i += 256) sum += __expf(sp[i]-mx);
  sum = wave_sum_f(sum);
  if (lane == 0) red[wv] = sum;
  __syncthreads();
  sum = red[0]+red[1]+red[2]+red[3];
  float inv = 1.f/sum;
  for (int i = tid; i < S_; i += 256)
    probs[(size_t)b*S_ + i] = __expf(sp[i]-mx)*inv;
}

// ---------------- K6: spectrum scatter --------------------------------------
__global__ __launch_bounds__(256) void k_spect(
    const float* __restrict__ peaks, const float* __restrict__ probs,
    float* __restrict__ spect){
  __shared__ float bins[512];
  int b = blockIdx.x, tid = threadIdx.x;
  bins[tid] = 0.f; bins[tid+256] = 0.f;
  __syncthreads();
  for (int i = tid; i < S_*M_; i += 256){
    int s = i >> 3, m = i & 7;
    const float* pk = peaks + (((size_t)b*S_ + s)*M_ + m)*2;
    float mass = pk[0], inten = pk[1];
    float p = probs[(size_t)b*S_ + s];
    int bin = (int)rintf(mass);
    bin = min(max(bin, 0), 511);
    atomicAdd(&bins[bin], inten*p);
  }
  __syncthreads();
  spect[(size_t)b*512 + tid]       = bins[tid];
  spect[(size_t)b*512 + tid + 256] = bins[tid+256];
}

// ---------------- launcher --------------------------------------------------
extern "C" void kernel_launch(void* const* d_in, const int* in_sizes, int n_in,
                              void* d_out, int out_size, void* d_ws, size_t ws_size,
                              hipStream_t stream) {
  const float* vf       = (const float*)d_in[0];
  const float* mask     = (const float*)d_in[1];
  const float* eoh      = (const float*)d_in[2];
  const float* subs     = (const float*)d_in[4];
  const float* peaks    = (const float*)d_in[5];
  const float* ln_sub_g = (const float*)d_in[6];
  const float* ln_sub_b = (const float*)d_in[7];
  const float* W_ih     = (const float*)d_in[8];
  const float* W_hh     = (const float*)d_in[9];
  const float* b_ih     = (const float*)d_in[10];
  const float* b_hh     = (const float*)d_in[11];
  const float* W1       = (const float*)d_in[12];
  const float* b1       = (const float*)d_in[13];
  const float* W2a      = (const float*)d_in[14];
  const float* b2a      = (const float*)d_in[15];
  const float* W2b      = (const float*)d_in[16];
  const float* b2b      = (const float*)d_in[17];
  const float* ln_pre_g = (const float*)d_in[18];
  const float* ln_pre_b = (const float*)d_in[19];
  const float* Ws       = (const float*)d_in[20];
  const float* bs       = (const float*)d_in[21];
  float* out = (float*)d_out;            // [0,8192) spect, [8192,73728) probs
  float* probs_out = out + (size_t)B_*512;

  // workspace carve — ~155 MB (ws >= ~206 MB proven)
  char* w = (char*)d_ws;
  float* scores = (float*)w;     w += (size_t)BS_*4;
  _Float16* Wcat = (_Float16*)w; w += (size_t)NG_*KC_*2;       // ~2 MB
  _Float16* W1h  = (_Float16*)w; w += (size_t)G_*G_*2;
  _Float16* W2ah = (_Float16*)w; w += (size_t)G_*G_*2;
  _Float16* W2bh = (_Float16*)w; w += (size_t)G_*G_*2;
  _Float16* Abuf = (_Float16*)w; w += (size_t)BS_*KC_*2;       // 84 MB
  _Float16* bufh0 = (_Float16*)w;                              // 67 MB (H)
  _Float16* bufh1 = Abuf;        // FF ping-pong reuses A region (84 >= 67 MB)

  k_cvt<<<(G_*G_/4+255)/256, 256, 0, stream>>>(W1,  W1h,  G_*G_);
  k_cvt<<<(G_*G_/4+255)/256, 256, 0, stream>>>(W2a, W2ah, G_*G_);
  k_cvt<<<(G_*G_/4+255)/256, 256, 0, stream>>>(W2b, W2bh, G_*G_);
  k_buildw<<<NG_, 64, 0, stream>>>(W_hh, W_ih, Wcat);
  k_prep_mfma<<<dim3(S_/128, B_), 256, 0, stream>>>(vf, mask, eoh, subs,
                                                    ln_sub_g, ln_sub_b, Abuf);
  k_gru_fused<<<dim3(8, 512), 512, 0, stream>>>(Abuf, Wcat, b_ih, b_hh, bufh0);
  k_gemm<<<dim3(8, 256), 256, 0, stream>>>(bufh0, W1h,  b1,  bufh1);
  k_gemm<<<dim3(8, 256), 256, 0, stream>>>(bufh1, W2ah, b2a, bufh0);
  k_gemm<<<dim3(8, 256), 256, 0, stream>>>(bufh0, W2bh, b2b, bufh1);
  k_ln_score<<<BS_/32, 256, 0, stream>>>(bufh1, ln_pre_g, ln_pre_b, Ws, bs, scores);
  k_softmax<<<B_, 256, 0, stream>>>(scores, probs_out);
  k_spect<<<B_, 256, 0, stream>>>(peaks, probs_out, out);
}